// Round 1
// baseline (1206.112 us; speedup 1.0000x reference)
//
#include <hip/hip_runtime.h>
#include <hip/hip_bf16.h>

#define B_ 2
#define S_ 4096
#define HID_ 2048
#define NH_ 32
#define NKV_ 8
#define HD_ 64
#define GROUPS_ 4

typedef short short8 __attribute__((ext_vector_type(8)));
typedef float floatx4 __attribute__((ext_vector_type(4)));

__device__ __forceinline__ float bf2f(unsigned short u){
  union { unsigned int i; float f; } v; v.i = ((unsigned int)u) << 16; return v.f;
}
__device__ __forceinline__ unsigned short f2bf(float f){
  union { float f; unsigned int i; } v; v.f = f;
  unsigned int i = v.i;
  unsigned int r = (i + 0x7fffu + ((i >> 16) & 1u)) >> 16;  // RNE
  return (unsigned short)r;
}

// ---------------- fp32 -> bf16 bulk convert (hidden_states) ----------------
__global__ void conv_bf16(const float* __restrict__ x, unsigned short* __restrict__ y, int n4){
  int i = blockIdx.x * 256 + threadIdx.x;
  if (i < n4){
    float4 v = ((const float4*)x)[i];
    ushort4 o;
    o.x = f2bf(v.x); o.y = f2bf(v.y); o.z = f2bf(v.z); o.w = f2bf(v.w);
    ((ushort4*)y)[i] = o;
  }
}

// ---------------- W[K,N] fp32 -> Wt[N,K] bf16 (tiled transpose) ----------------
__global__ void transpose_to_bf16(const float* __restrict__ W, unsigned short* __restrict__ Wt,
                                  int K, int N){
  __shared__ float tile[32][33];
  int n0 = blockIdx.x * 32, k0 = blockIdx.y * 32;
  int tx = threadIdx.x, ty = threadIdx.y;   // 32 x 8
  #pragma unroll
  for (int j = 0; j < 4; j++)
    tile[ty + j*8][tx] = W[(size_t)(k0 + ty + j*8) * N + n0 + tx];
  __syncthreads();
  #pragma unroll
  for (int j = 0; j < 4; j++)
    Wt[(size_t)(n0 + ty + j*8) * K + k0 + tx] = f2bf(tile[tx][ty + j*8]);
}

// ---------------- C[M,N] fp32 = A[M,K] bf16 @ Bt[N,K]^T bf16 ----------------
// 128x128 tile, BK=32, 256 threads (4 waves), each wave 64x64 via 4x4 mfma_16x16x32.
__global__ __launch_bounds__(256) void gemm_bt(
    const unsigned short* __restrict__ A, const unsigned short* __restrict__ Bt,
    float* __restrict__ C, int M, int N, int K)
{
  __shared__ __align__(16) unsigned short As[128 * 32];
  __shared__ __align__(16) unsigned short Bs[128 * 32];
  int tid = threadIdx.x;
  int m0 = blockIdx.y * 128, n0 = blockIdx.x * 128;
  int wave = tid >> 6, lane = tid & 63;
  int wm = (wave & 1) * 64, wn = (wave >> 1) * 64;
  int l15 = lane & 15, quad = lane >> 4;

  floatx4 acc[4][4] = {};

  int srow = tid >> 2;          // 0..63
  int scol = (tid & 3) * 8;     // 0,8,16,24

  for (int k0 = 0; k0 < K; k0 += 32){
    #pragma unroll
    for (int i = 0; i < 2; i++){
      int row = i * 64 + srow;
      *(uint4*)(&As[row * 32 + scol]) = *(const uint4*)(&A[(size_t)(m0 + row) * K + k0 + scol]);
      *(uint4*)(&Bs[row * 32 + scol]) = *(const uint4*)(&Bt[(size_t)(n0 + row) * K + k0 + scol]);
    }
    __syncthreads();
    short8 af[4], bfr[4];
    #pragma unroll
    for (int i = 0; i < 4; i++){
      af[i]  = *(const short8*)(&As[(wm + i*16 + l15) * 32 + quad * 8]);
      bfr[i] = *(const short8*)(&Bs[(wn + i*16 + l15) * 32 + quad * 8]);
    }
    #pragma unroll
    for (int mi = 0; mi < 4; mi++)
      #pragma unroll
      for (int ni = 0; ni < 4; ni++)
        acc[mi][ni] = __builtin_amdgcn_mfma_f32_16x16x32_bf16(af[mi], bfr[ni], acc[mi][ni], 0, 0, 0);
    __syncthreads();
  }

  #pragma unroll
  for (int mi = 0; mi < 4; mi++){
    int row = m0 + wm + mi*16 + quad*4;
    #pragma unroll
    for (int ni = 0; ni < 4; ni++){
      int col = n0 + wn + ni*16 + l15;
      #pragma unroll
      for (int r = 0; r < 4; r++)
        C[(size_t)(row + r) * N + col] = acc[mi][ni][r];
    }
  }
}

// ---------------- RoPE + kappa for Q: [B,S,NH,HD] fp32 -> [B,NH,S,HD] bf16 ----------------
__global__ void rope_kappa_q(const float* __restrict__ Qlin, unsigned short* __restrict__ Qk){
  int idx = blockIdx.x * 256 + threadIdx.x;    // B*S*NH*32 = 2^23 threads
  int i = idx & 31;
  int n = (idx >> 5) & (NH_ - 1);
  int s = (idx >> 10) & (S_ - 1);
  int b = idx >> 22;
  float invf = exp2f(-(float)i * (13.287712379549449f / 32.0f));  // 10000^(-i/32)
  float ang = (float)s * invf;
  float c = cosf(ang), sn = sinf(ang);
  size_t in_o = ((size_t)(b * S_ + s) * NH_ + n) * HD_;
  float x1 = Qlin[in_o + i];
  float x2 = Qlin[in_o + i + 32];
  float r1 = x1 * c - x2 * sn;
  float r2 = x2 * c + x1 * sn;
  r1 = r1 > 0.f ? r1 + 1.f : __expf(r1);
  r2 = r2 > 0.f ? r2 + 1.f : __expf(r2);
  size_t o = ((size_t)(b * NH_ + n) * S_ + s) * HD_;
  Qk[o + i] = f2bf(r1);
  Qk[o + i + 32] = f2bf(r2);
}

// ---------------- RoPE + kappa for K: [B,S,NKV,HD] fp32 -> [B,NKV,S,HD] bf16 ----------------
__global__ void rope_kappa_k(const float* __restrict__ Klin, unsigned short* __restrict__ Kk){
  int idx = blockIdx.x * 256 + threadIdx.x;    // B*S*NKV*32 = 2^21 threads
  int i = idx & 31;
  int kv = (idx >> 5) & (NKV_ - 1);
  int s = (idx >> 8) & (S_ - 1);
  int b = idx >> 20;
  float invf = exp2f(-(float)i * (13.287712379549449f / 32.0f));
  float ang = (float)s * invf;
  float c = cosf(ang), sn = sinf(ang);
  size_t in_o = ((size_t)(b * S_ + s) * NKV_ + kv) * HD_;
  float x1 = Klin[in_o + i];
  float x2 = Klin[in_o + i + 32];
  float r1 = x1 * c - x2 * sn;
  float r2 = x2 * c + x1 * sn;
  r1 = r1 > 0.f ? r1 + 1.f : __expf(r1);
  r2 = r2 > 0.f ? r2 + 1.f : __expf(r2);
  size_t o = ((size_t)(b * NKV_ + kv) * S_ + s) * HD_;
  Kk[o + i] = f2bf(r1);
  Kk[o + i + 32] = f2bf(r2);
}

// ---------------- Qg[b,n,d] = mean_s Qk[b,n,s,d] ----------------
__global__ __launch_bounds__(256) void qg_mean(const unsigned short* __restrict__ Qk, float* __restrict__ Qg){
  int bn = blockIdx.x;
  int tid = threadIdx.x;
  int d = tid & 63, part = tid >> 6;
  const unsigned short* base = Qk + (size_t)bn * S_ * HD_;
  float sum = 0.f;
  for (int s = part; s < S_; s += 4) sum += bf2f(base[(size_t)s * HD_ + d]);
  __shared__ float red[256];
  red[tid] = sum;
  __syncthreads();
  if (tid < 64){
    float t = red[tid] + red[tid + 64] + red[tid + 128] + red[tid + 192];
    Qg[bn * 64 + tid] = t * (1.0f / (float)S_);
  }
}

// ---------------- logits + softmax*S -> alpha[b,n,s] ----------------
__global__ __launch_bounds__(256) void alpha_kernel(const unsigned short* __restrict__ Kk,
                                                    const float* __restrict__ Qg,
                                                    float* __restrict__ alpha){
  int bn = blockIdx.x;
  int b = bn / NH_, n = bn % NH_, kv = n / GROUPS_;
  int tid = threadIdx.x;
  __shared__ float qg[64];
  if (tid < 64) qg[tid] = Qg[bn * 64 + tid];
  __syncthreads();
  const unsigned short* kb = Kk + (size_t)(b * NKV_ + kv) * S_ * HD_;
  float l[16];
  float mymax = -1e30f;
  #pragma unroll
  for (int j = 0; j < 16; j++){
    int s = j * 256 + tid;
    const unsigned short* row = kb + (size_t)s * HD_;
    float acc = 0.f;
    #pragma unroll
    for (int d = 0; d < 64; d++) acc += qg[d] * bf2f(row[d]);
    l[j] = acc;
    mymax = fmaxf(mymax, acc);
  }
  __shared__ float red[256];
  red[tid] = mymax; __syncthreads();
  for (int st = 128; st > 0; st >>= 1){
    if (tid < st) red[tid] = fmaxf(red[tid], red[tid + st]);
    __syncthreads();
  }
  float gmax = red[0];
  __syncthreads();
  float mysum = 0.f;
  #pragma unroll
  for (int j = 0; j < 16; j++){ l[j] = __expf(l[j] - gmax); mysum += l[j]; }
  red[tid] = mysum; __syncthreads();
  for (int st = 128; st > 0; st >>= 1){
    if (tid < st) red[tid] += red[tid + st];
    __syncthreads();
  }
  float inv = (float)S_ / red[0];
  #pragma unroll
  for (int j = 0; j < 16; j++)
    alpha[(size_t)bn * S_ + j * 256 + tid] = l[j] * inv;
}

// ---------------- outer_sum[b,n,d,f] += sum_s alpha*Kk*V (split-S, atomics) ----------------
#define OS_CHUNK 512
__global__ __launch_bounds__(256) void outer_sum_kernel(const unsigned short* __restrict__ Kk,
                                                        const float* __restrict__ V,
                                                        const float* __restrict__ alpha,
                                                        float* __restrict__ osum){
  int bn = blockIdx.x, chunk = blockIdx.y;
  int b = bn / NH_, n = bn % NH_, kv = n / GROUPS_;
  int tid = threadIdx.x;
  int d = tid >> 2, fb = (tid & 3) * 16;
  __shared__ float ak[64][64];
  __shared__ float vv[64][64];
  float acc[16] = {};
  int s0 = chunk * OS_CHUNK;
  const unsigned short* kb = Kk + (size_t)(b * NKV_ + kv) * S_ * HD_;
  const float* ab = alpha + (size_t)bn * S_;
  for (int ss = s0; ss < s0 + OS_CHUNK; ss += 64){
    #pragma unroll
    for (int j = 0; j < 16; j++){
      int idx = j * 256 + tid;
      int si = idx >> 6, dd = idx & 63;
      ak[si][dd] = ab[ss + si] * bf2f(kb[(size_t)(ss + si) * HD_ + dd]);
      vv[si][dd] = V[((size_t)(b * S_ + ss + si) * NKV_ + kv) * HD_ + dd];
    }
    __syncthreads();
    #pragma unroll 8
    for (int si = 0; si < 64; si++){
      float a = ak[si][d];
      #pragma unroll
      for (int j = 0; j < 16; j++) acc[j] += a * vv[si][fb + j];
    }
    __syncthreads();
  }
  float* ob = osum + (size_t)bn * 4096 + d * 64 + fb;
  #pragma unroll
  for (int j = 0; j < 16; j++) atomicAdd(&ob[j], acc[j]);
}

// ---------------- ctx[b,s,n*64+f] = Xphi[b,s,n,f] * sum_d Qk[b,n,s,d]*osum[b,n,d,f] ----------------
__global__ __launch_bounds__(256) void ctx_kernel(const unsigned short* __restrict__ Qk,
                                                  const float* __restrict__ osum,
                                                  const float* __restrict__ Xphi,
                                                  unsigned short* __restrict__ ctx){
  int bn = blockIdx.x, sc = blockIdx.y;
  int b = bn / NH_, n = bn % NH_;
  int tid = threadIdx.x;
  __shared__ float os[64][65];
  __shared__ float qs[64][65];
  #pragma unroll
  for (int j = 0; j < 16; j++){
    int idx = j * 256 + tid;
    int r = idx >> 6, cix = idx & 63;
    os[r][cix] = osum[(size_t)bn * 4096 + idx];
    qs[r][cix] = bf2f(Qk[((size_t)bn * S_ + sc * 64 + r) * HD_ + cix]);
  }
  __syncthreads();
  int sl = tid >> 2, fb = (tid & 3) * 16;
  float r[16] = {};
  #pragma unroll 8
  for (int d = 0; d < 64; d++){
    float q = qs[sl][d];
    #pragma unroll
    for (int j = 0; j < 16; j++) r[j] += q * os[d][fb + j];
  }
  int s = sc * 64 + sl;
  const float* xp = Xphi + ((size_t)(b * S_ + s) * NH_ + n) * HD_ + fb;
  unsigned short* cp = ctx + (size_t)(b * S_ + s) * HID_ + n * HD_ + fb;
  #pragma unroll
  for (int j = 0; j < 16; j++) cp[j] = f2bf(xp[j] * r[j]);
}

extern "C" void kernel_launch(void* const* d_in, const int* in_sizes, int n_in,
                              void* d_out, int out_size, void* d_ws, size_t ws_size,
                              hipStream_t stream) {
  const float* hs   = (const float*)d_in[0];
  const float* Wq   = (const float*)d_in[1];
  const float* Wk   = (const float*)d_in[2];
  const float* Wv   = (const float*)d_in[3];
  const float* Wphi = (const float*)d_in[4];
  const float* Wo   = (const float*)d_in[5];
  float* out = (float*)d_out;

  char* ws = (char*)d_ws;
  const size_t M = (size_t)B_ * S_;          // 8192
  size_t off = 0;
  auto alloc = [&](size_t bytes){ size_t o = off; off += (bytes + 255) & ~(size_t)255; return o; };

  size_t off_hsb  = alloc(M * HID_ * 2);                 // 32MB bf16
  size_t off_wqt  = alloc((size_t)HID_ * HID_ * 2);      // 8MB
  size_t off_wkt  = alloc((size_t)HID_ * 512 * 2);       // 2MB
  size_t off_wvt  = alloc((size_t)HID_ * 512 * 2);       // 2MB
  size_t off_wpt  = alloc((size_t)HID_ * HID_ * 2);      // 8MB
  size_t off_wot  = alloc((size_t)HID_ * HID_ * 2);      // 8MB
  size_t off_qlin = alloc(M * HID_ * 4);                 // 64MB fp32 (later reused for Xphi)
  size_t off_klin = alloc(M * 512 * 4);                  // 16MB fp32
  size_t off_v    = alloc(M * 512 * 4);                  // 16MB fp32
  size_t off_qk   = alloc(M * HID_ * 2);                 // 32MB bf16 [B,NH,S,D]
  size_t off_kk   = alloc(M * 512 * 2);                  // 8MB  bf16 [B,NKV,S,D]
  size_t off_qg   = alloc(64 * 64 * 4);
  size_t off_alph = alloc((size_t)B_ * NH_ * S_ * 4);    // 1MB
  size_t off_osum = alloc((size_t)B_ * NH_ * 4096 * 4);  // 1MB
  size_t off_ctx  = off_klin;                            // reuse klin+v region (32MB bf16)
  (void)ws_size;

  unsigned short* hsb = (unsigned short*)(ws + off_hsb);
  unsigned short* wqt = (unsigned short*)(ws + off_wqt);
  unsigned short* wkt = (unsigned short*)(ws + off_wkt);
  unsigned short* wvt = (unsigned short*)(ws + off_wvt);
  unsigned short* wpt = (unsigned short*)(ws + off_wpt);
  unsigned short* wot = (unsigned short*)(ws + off_wot);
  float* qlin = (float*)(ws + off_qlin);
  float* klin = (float*)(ws + off_klin);
  float* vbuf = (float*)(ws + off_v);
  unsigned short* qk = (unsigned short*)(ws + off_qk);
  unsigned short* kk = (unsigned short*)(ws + off_kk);
  float* qg   = (float*)(ws + off_qg);
  float* alph = (float*)(ws + off_alph);
  float* osum = (float*)(ws + off_osum);
  unsigned short* ctx = (unsigned short*)(ws + off_ctx);

  // 1. hs -> bf16
  conv_bf16<<<(int)(M * HID_ / 4 / 256), 256, 0, stream>>>(hs, hsb, (int)(M * HID_ / 4));
  // 2. weight transposes (W[K,N] -> Wt[N,K] bf16)
  transpose_to_bf16<<<dim3(HID_/32, HID_/32), dim3(32,8), 0, stream>>>(Wq, wqt, HID_, HID_);
  transpose_to_bf16<<<dim3(512/32,  HID_/32), dim3(32,8), 0, stream>>>(Wk, wkt, HID_, 512);
  transpose_to_bf16<<<dim3(512/32,  HID_/32), dim3(32,8), 0, stream>>>(Wv, wvt, HID_, 512);
  transpose_to_bf16<<<dim3(HID_/32, HID_/32), dim3(32,8), 0, stream>>>(Wphi, wpt, HID_, HID_);
  transpose_to_bf16<<<dim3(HID_/32, HID_/32), dim3(32,8), 0, stream>>>(Wo, wot, HID_, HID_);
  // 3-5. QKV projections
  gemm_bt<<<dim3(HID_/128, M/128), 256, 0, stream>>>(hsb, wqt, qlin, (int)M, HID_, HID_);
  gemm_bt<<<dim3(512/128,  M/128), 256, 0, stream>>>(hsb, wkt, klin, (int)M, 512, HID_);
  gemm_bt<<<dim3(512/128,  M/128), 256, 0, stream>>>(hsb, wvt, vbuf, (int)M, 512, HID_);
  // 6-7. RoPE + kappa (+ layout to [B,H,S,D])
  rope_kappa_q<<<(int)(M * NH_ * 32 / 256), 256, 0, stream>>>(qlin, qk);
  rope_kappa_k<<<(int)(M * NKV_ * 32 / 256), 256, 0, stream>>>(klin, kk);
  // 8. global query
  qg_mean<<<B_ * NH_, 256, 0, stream>>>(qk, qg);
  // 9. logits + softmax * S
  alpha_kernel<<<B_ * NH_, 256, 0, stream>>>(kk, qg, alph);
  // 10. outer_sum (zero-init + split-S atomics)
  hipMemsetAsync(osum, 0, (size_t)B_ * NH_ * 4096 * 4, stream);
  outer_sum_kernel<<<dim3(B_ * NH_, S_ / OS_CHUNK), 256, 0, stream>>>(kk, vbuf, alph, osum);
  // 11. Xphi projection (reuses qlin region)
  gemm_bt<<<dim3(HID_/128, M/128), 256, 0, stream>>>(hsb, wpt, qlin, (int)M, HID_, HID_);
  // 12. ctx = Xphi * (Qk @ osum)  -> bf16 (reuses klin+v region)
  ctx_kernel<<<dim3(B_ * NH_, S_ / 64), 256, 0, stream>>>(qk, osum, qlin, ctx);
  // 13. out = ctx @ Wo
  gemm_bt<<<dim3(HID_/128, M/128), 256, 0, stream>>>(ctx, wot, out, (int)M, HID_, HID_);
}

// Round 2
// 946.707 us; speedup vs baseline: 1.2740x; 1.2740x over previous
//
#include <hip/hip_runtime.h>
#include <hip/hip_bf16.h>

#define B_ 2
#define S_ 4096
#define HID_ 2048
#define NH_ 32
#define NKV_ 8
#define HD_ 64
#define GROUPS_ 4

typedef short short8 __attribute__((ext_vector_type(8)));
typedef float floatx4 __attribute__((ext_vector_type(4)));

__device__ __forceinline__ float bf2f(unsigned short u){
  union { unsigned int i; float f; } v; v.i = ((unsigned int)u) << 16; return v.f;
}
__device__ __forceinline__ unsigned short f2bf(float f){
  union { float f; unsigned int i; } v; v.f = f;
  unsigned int i = v.i;
  unsigned int r = (i + 0x7fffu + ((i >> 16) & 1u)) >> 16;  // RNE
  return (unsigned short)r;
}

// async global->LDS, 16B per lane, LDS dest = wave-uniform base + lane*16
__device__ __forceinline__ void async_copy16(unsigned short* lds, const unsigned short* g){
  __builtin_amdgcn_global_load_lds((const __attribute__((address_space(1))) void*)g,
                                   (__attribute__((address_space(3))) void*)lds,
                                   16, 0, 0);
}

// ---------------- fp32 -> bf16 bulk convert (hidden_states) ----------------
__global__ void conv_bf16(const float* __restrict__ x, unsigned short* __restrict__ y, int n4){
  int i = blockIdx.x * 256 + threadIdx.x;
  if (i < n4){
    float4 v = ((const float4*)x)[i];
    ushort4 o;
    o.x = f2bf(v.x); o.y = f2bf(v.y); o.z = f2bf(v.z); o.w = f2bf(v.w);
    ((ushort4*)y)[i] = o;
  }
}

// ---------------- W[K,N] fp32 -> Wt[N,K] bf16 (tiled transpose) ----------------
__global__ void transpose_to_bf16(const float* __restrict__ W, unsigned short* __restrict__ Wt,
                                  int K, int N){
  __shared__ float tile[32][33];
  int n0 = blockIdx.x * 32, k0 = blockIdx.y * 32;
  int tx = threadIdx.x, ty = threadIdx.y;   // 32 x 8
  #pragma unroll
  for (int j = 0; j < 4; j++)
    tile[ty + j*8][tx] = W[(size_t)(k0 + ty + j*8) * N + n0 + tx];
  __syncthreads();
  #pragma unroll
  for (int j = 0; j < 4; j++)
    Wt[(size_t)(n0 + ty + j*8) * K + k0 + tx] = f2bf(tile[tx][ty + j*8]);
}

// ---------------- C[M,N] fp32 = A[M,K] bf16 @ Bt[N,K]^T bf16 ----------------
// 128x128 tile, BK=32, 256 threads (4 waves), 4x4 mfma_16x16x32 per wave.
// m97 structure: global_load_lds width=16 staging.
__global__ __launch_bounds__(256) void gemm_bt(
    const unsigned short* __restrict__ A, const unsigned short* __restrict__ Bt,
    float* __restrict__ C, int M, int N, int K)
{
  __shared__ __align__(16) unsigned short As[128 * 32];
  __shared__ __align__(16) unsigned short Bs[128 * 32];
  int tid = threadIdx.x;
  int m0 = blockIdx.y * 128, n0 = blockIdx.x * 128;
  int wave = tid >> 6, lane = tid & 63;
  int wm = (wave & 1) * 64, wn = (wave >> 1) * 64;
  int l15 = lane & 15, quad = lane >> 4;
  int lrow = lane >> 2, lcol = (lane & 3) * 8;   // staging: lane -> (row, col8)
  int wr0 = wave * 32;                           // wave's 32 staging rows

  const unsigned short* Ab = A  + (size_t)(m0 + wr0 + lrow) * K + lcol;
  const unsigned short* Bb = Bt + (size_t)(n0 + wr0 + lrow) * K + lcol;

  floatx4 acc[4][4] = {};

  for (int k0 = 0; k0 < K; k0 += 32){
    async_copy16(&As[(size_t)wr0 * 32],        Ab + k0);
    async_copy16(&As[(size_t)(wr0 + 16) * 32], Ab + (size_t)16 * K + k0);
    async_copy16(&Bs[(size_t)wr0 * 32],        Bb + k0);
    async_copy16(&Bs[(size_t)(wr0 + 16) * 32], Bb + (size_t)16 * K + k0);
    __syncthreads();
    short8 af[4], bfr[4];
    #pragma unroll
    for (int i = 0; i < 4; i++){
      af[i]  = *(const short8*)(&As[(wm + i*16 + l15) * 32 + quad * 8]);
      bfr[i] = *(const short8*)(&Bs[(wn + i*16 + l15) * 32 + quad * 8]);
    }
    #pragma unroll
    for (int mi = 0; mi < 4; mi++)
      #pragma unroll
      for (int ni = 0; ni < 4; ni++)
        acc[mi][ni] = __builtin_amdgcn_mfma_f32_16x16x32_bf16(af[mi], bfr[ni], acc[mi][ni], 0, 0, 0);
    __syncthreads();
  }

  #pragma unroll
  for (int mi = 0; mi < 4; mi++){
    int row = m0 + wm + mi*16 + quad*4;
    #pragma unroll
    for (int ni = 0; ni < 4; ni++){
      int col = n0 + wn + ni*16 + l15;
      #pragma unroll
      for (int r = 0; r < 4; r++)
        C[(size_t)(row + r) * N + col] = acc[mi][ni][r];
    }
  }
}

// ---------------- RoPE + kappa for Q: [B,S,NH,HD] fp32 -> [B,NH,S,HD] bf16 ----------------
__global__ void rope_kappa_q(const float* __restrict__ Qlin, unsigned short* __restrict__ Qk){
  int idx = blockIdx.x * 256 + threadIdx.x;    // B*S*NH*32 = 2^23 threads
  int i = idx & 31;
  int n = (idx >> 5) & (NH_ - 1);
  int s = (idx >> 10) & (S_ - 1);
  int b = idx >> 22;
  float invf = exp2f(-(float)i * (13.287712379549449f / 32.0f));  // 10000^(-i/32)
  float ang = (float)s * invf;
  float c = cosf(ang), sn = sinf(ang);
  size_t in_o = ((size_t)(b * S_ + s) * NH_ + n) * HD_;
  float x1 = Qlin[in_o + i];
  float x2 = Qlin[in_o + i + 32];
  float r1 = x1 * c - x2 * sn;
  float r2 = x2 * c + x1 * sn;
  r1 = r1 > 0.f ? r1 + 1.f : __expf(r1);
  r2 = r2 > 0.f ? r2 + 1.f : __expf(r2);
  size_t o = ((size_t)(b * NH_ + n) * S_ + s) * HD_;
  Qk[o + i] = f2bf(r1);
  Qk[o + i + 32] = f2bf(r2);
}

// ---------------- RoPE + kappa for K: [B,S,NKV,HD] fp32 -> [B,NKV,S,HD] bf16 ----------------
__global__ void rope_kappa_k(const float* __restrict__ Klin, unsigned short* __restrict__ Kk){
  int idx = blockIdx.x * 256 + threadIdx.x;    // B*S*NKV*32 = 2^21 threads
  int i = idx & 31;
  int kv = (idx >> 5) & (NKV_ - 1);
  int s = (idx >> 8) & (S_ - 1);
  int b = idx >> 20;
  float invf = exp2f(-(float)i * (13.287712379549449f / 32.0f));
  float ang = (float)s * invf;
  float c = cosf(ang), sn = sinf(ang);
  size_t in_o = ((size_t)(b * S_ + s) * NKV_ + kv) * HD_;
  float x1 = Klin[in_o + i];
  float x2 = Klin[in_o + i + 32];
  float r1 = x1 * c - x2 * sn;
  float r2 = x2 * c + x1 * sn;
  r1 = r1 > 0.f ? r1 + 1.f : __expf(r1);
  r2 = r2 > 0.f ? r2 + 1.f : __expf(r2);
  size_t o = ((size_t)(b * NKV_ + kv) * S_ + s) * HD_;
  Kk[o + i] = f2bf(r1);
  Kk[o + i + 32] = f2bf(r2);
}

// ---------------- Qg[b,n,d] = mean_s Qk[b,n,s,d]  (split-S, atomics) ----------------
__global__ __launch_bounds__(256) void qg_mean(const unsigned short* __restrict__ Qk,
                                               float* __restrict__ Qg){
  int bn = blockIdx.x, chunk = blockIdx.y;     // 64 x 16
  int tid = threadIdx.x;
  int dgrp = tid & 7, sgrp = tid >> 3;         // 8 d-chunks x 32 s-rows
  const unsigned short* base = Qk + (size_t)bn * S_ * HD_
                             + (size_t)(chunk * 256 + sgrp) * HD_ + dgrp * 8;
  float acc[8] = {};
  #pragma unroll
  for (int i = 0; i < 8; i++){
    short8 v = *(const short8*)(base + (size_t)i * 32 * HD_);
    #pragma unroll
    for (int e = 0; e < 8; e++) acc[e] += bf2f((unsigned short)v[e]);
  }
  __shared__ float red[256][8];
  #pragma unroll
  for (int e = 0; e < 8; e++) red[tid][e] = acc[e];
  __syncthreads();
  if (tid < 64){
    int dg = tid >> 3, e = tid & 7;
    float s = 0.f;
    #pragma unroll
    for (int g = 0; g < 32; g++) s += red[g * 8 + dg][e];
    atomicAdd(&Qg[bn * 64 + tid], s * (1.0f / (float)S_));
  }
}

// ---------------- logits[b,n,s] = dot(Qg[b,n], Kk[b,kv,s]) ----------------
__global__ __launch_bounds__(256) void logits_kernel(const unsigned short* __restrict__ Kk,
                                                     const float* __restrict__ Qg,
                                                     float* __restrict__ logits){
  int bn = blockIdx.x, chunk = blockIdx.y;     // 64 x 16
  int b = bn / NH_, n = bn % NH_, kv = n / GROUPS_;
  int tid = threadIdx.x;
  __shared__ float qg[64];
  if (tid < 64) qg[tid] = Qg[bn * 64 + tid];
  __syncthreads();
  int s = chunk * 256 + tid;
  const unsigned short* row = Kk + ((size_t)(b * NKV_ + kv) * S_ + s) * HD_;
  float acc = 0.f;
  #pragma unroll
  for (int c = 0; c < 8; c++){
    short8 v = *(const short8*)(row + c * 8);
    #pragma unroll
    for (int e = 0; e < 8; e++) acc += qg[c * 8 + e] * bf2f((unsigned short)v[e]);
  }
  logits[(size_t)bn * S_ + s] = acc;
}

// ---------------- softmax * S over logits -> alpha (in place OK) ----------------
__global__ __launch_bounds__(256) void softmax_kernel(const float* __restrict__ logits,
                                                      float* __restrict__ alpha){
  int bn = blockIdx.x;
  int tid = threadIdx.x;
  float l[16];
  float mymax = -1e30f;
  #pragma unroll
  for (int j = 0; j < 16; j++){
    l[j] = logits[(size_t)bn * S_ + j * 256 + tid];
    mymax = fmaxf(mymax, l[j]);
  }
  __shared__ float red[256];
  red[tid] = mymax; __syncthreads();
  for (int st = 128; st > 0; st >>= 1){
    if (tid < st) red[tid] = fmaxf(red[tid], red[tid + st]);
    __syncthreads();
  }
  float gmax = red[0];
  __syncthreads();
  float mysum = 0.f;
  #pragma unroll
  for (int j = 0; j < 16; j++){ l[j] = __expf(l[j] - gmax); mysum += l[j]; }
  red[tid] = mysum; __syncthreads();
  for (int st = 128; st > 0; st >>= 1){
    if (tid < st) red[tid] += red[tid + st];
    __syncthreads();
  }
  float inv = (float)S_ / red[0];
  #pragma unroll
  for (int j = 0; j < 16; j++)
    alpha[(size_t)bn * S_ + j * 256 + tid] = l[j] * inv;
}

// ---------------- outer_sum[b,n,d,f] += sum_s alpha*Kk*V (split-S, atomics) ----------------
#define OS_CHUNK 512
__global__ __launch_bounds__(256) void outer_sum_kernel(const unsigned short* __restrict__ Kk,
                                                        const float* __restrict__ V,
                                                        const float* __restrict__ alpha,
                                                        float* __restrict__ osum){
  int bn = blockIdx.x, chunk = blockIdx.y;
  int b = bn / NH_, n = bn % NH_, kv = n / GROUPS_;
  int tid = threadIdx.x;
  int d = tid >> 2, fb = (tid & 3) * 16;
  __shared__ float ak[64][64];
  __shared__ float vv[64][64];
  float acc[16] = {};
  int s0 = chunk * OS_CHUNK;
  const unsigned short* kb = Kk + (size_t)(b * NKV_ + kv) * S_ * HD_;
  const float* ab = alpha + (size_t)bn * S_;
  for (int ss = s0; ss < s0 + OS_CHUNK; ss += 64){
    #pragma unroll
    for (int j = 0; j < 16; j++){
      int idx = j * 256 + tid;
      int si = idx >> 6, dd = idx & 63;
      ak[si][dd] = ab[ss + si] * bf2f(kb[(size_t)(ss + si) * HD_ + dd]);
      vv[si][dd] = V[((size_t)(b * S_ + ss + si) * NKV_ + kv) * HD_ + dd];
    }
    __syncthreads();
    #pragma unroll 8
    for (int si = 0; si < 64; si++){
      float a = ak[si][d];
      #pragma unroll
      for (int j = 0; j < 16; j++) acc[j] += a * vv[si][fb + j];
    }
    __syncthreads();
  }
  float* ob = osum + (size_t)bn * 4096 + d * 64 + fb;
  #pragma unroll
  for (int j = 0; j < 16; j++) atomicAdd(&ob[j], acc[j]);
}

// ---------------- ctx[b,s,n*64+f] = Xphi[b,s,n,f] * sum_d Qk[b,n,s,d]*osum[b,n,d,f] ----------------
__global__ __launch_bounds__(256) void ctx_kernel(const unsigned short* __restrict__ Qk,
                                                  const float* __restrict__ osum,
                                                  const float* __restrict__ Xphi,
                                                  unsigned short* __restrict__ ctx){
  int bn = blockIdx.x, sc = blockIdx.y;
  int b = bn / NH_, n = bn % NH_;
  int tid = threadIdx.x;
  __shared__ float os[64][65];
  __shared__ float qs[64][65];
  #pragma unroll
  for (int j = 0; j < 16; j++){
    int idx = j * 256 + tid;
    int r = idx >> 6, cix = idx & 63;
    os[r][cix] = osum[(size_t)bn * 4096 + idx];
    qs[r][cix] = bf2f(Qk[((size_t)bn * S_ + sc * 64 + r) * HD_ + cix]);
  }
  __syncthreads();
  int sl = tid >> 2, fb = (tid & 3) * 16;
  float r[16] = {};
  #pragma unroll 8
  for (int d = 0; d < 64; d++){
    float q = qs[sl][d];
    #pragma unroll
    for (int j = 0; j < 16; j++) r[j] += q * os[d][fb + j];
  }
  int s = sc * 64 + sl;
  const float* xp = Xphi + ((size_t)(b * S_ + s) * NH_ + n) * HD_ + fb;
  unsigned short* cp = ctx + (size_t)(b * S_ + s) * HID_ + n * HD_ + fb;
  #pragma unroll
  for (int j = 0; j < 16; j++) cp[j] = f2bf(xp[j] * r[j]);
}

extern "C" void kernel_launch(void* const* d_in, const int* in_sizes, int n_in,
                              void* d_out, int out_size, void* d_ws, size_t ws_size,
                              hipStream_t stream) {
  const float* hs   = (const float*)d_in[0];
  const float* Wq   = (const float*)d_in[1];
  const float* Wk   = (const float*)d_in[2];
  const float* Wv   = (const float*)d_in[3];
  const float* Wphi = (const float*)d_in[4];
  const float* Wo   = (const float*)d_in[5];
  float* out = (float*)d_out;

  char* ws = (char*)d_ws;
  const size_t M = (size_t)B_ * S_;          // 8192
  size_t off = 0;
  auto alloc = [&](size_t bytes){ size_t o = off; off += (bytes + 255) & ~(size_t)255; return o; };

  size_t off_hsb  = alloc(M * HID_ * 2);                 // 32MB bf16
  size_t off_wqt  = alloc((size_t)HID_ * HID_ * 2);      // 8MB
  size_t off_wkt  = alloc((size_t)HID_ * 512 * 2);       // 2MB
  size_t off_wvt  = alloc((size_t)HID_ * 512 * 2);       // 2MB
  size_t off_wpt  = alloc((size_t)HID_ * HID_ * 2);      // 8MB
  size_t off_wot  = alloc((size_t)HID_ * HID_ * 2);      // 8MB
  size_t off_qlin = alloc(M * HID_ * 4);                 // 64MB fp32 (later reused for Xphi)
  size_t off_klin = alloc(M * 512 * 4);                  // 16MB fp32
  size_t off_v    = alloc(M * 512 * 4);                  // 16MB fp32
  size_t off_qk   = alloc(M * HID_ * 2);                 // 32MB bf16 [B,NH,S,D]
  size_t off_kk   = alloc(M * 512 * 2);                  // 8MB  bf16 [B,NKV,S,D]
  size_t off_qg   = alloc(64 * 64 * 4);
  size_t off_alph = alloc((size_t)B_ * NH_ * S_ * 4);    // 1MB
  size_t off_osum = alloc((size_t)B_ * NH_ * 4096 * 4);  // 1MB
  size_t off_ctx  = off_klin;                            // reuse klin+v region (32MB bf16)
  (void)ws_size;

  unsigned short* hsb = (unsigned short*)(ws + off_hsb);
  unsigned short* wqt = (unsigned short*)(ws + off_wqt);
  unsigned short* wkt = (unsigned short*)(ws + off_wkt);
  unsigned short* wvt = (unsigned short*)(ws + off_wvt);
  unsigned short* wpt = (unsigned short*)(ws + off_wpt);
  unsigned short* wot = (unsigned short*)(ws + off_wot);
  float* qlin = (float*)(ws + off_qlin);
  float* klin = (float*)(ws + off_klin);
  float* vbuf = (float*)(ws + off_v);
  unsigned short* qk = (unsigned short*)(ws + off_qk);
  unsigned short* kk = (unsigned short*)(ws + off_kk);
  float* qg   = (float*)(ws + off_qg);
  float* alph = (float*)(ws + off_alph);
  float* osum = (float*)(ws + off_osum);
  unsigned short* ctx = (unsigned short*)(ws + off_ctx);

  // 1. hs -> bf16
  conv_bf16<<<(int)(M * HID_ / 4 / 256), 256, 0, stream>>>(hs, hsb, (int)(M * HID_ / 4));
  // 2. weight transposes (W[K,N] -> Wt[N,K] bf16)
  transpose_to_bf16<<<dim3(HID_/32, HID_/32), dim3(32,8), 0, stream>>>(Wq, wqt, HID_, HID_);
  transpose_to_bf16<<<dim3(512/32,  HID_/32), dim3(32,8), 0, stream>>>(Wk, wkt, HID_, 512);
  transpose_to_bf16<<<dim3(512/32,  HID_/32), dim3(32,8), 0, stream>>>(Wv, wvt, HID_, 512);
  transpose_to_bf16<<<dim3(HID_/32, HID_/32), dim3(32,8), 0, stream>>>(Wphi, wpt, HID_, HID_);
  transpose_to_bf16<<<dim3(HID_/32, HID_/32), dim3(32,8), 0, stream>>>(Wo, wot, HID_, HID_);
  // 3-5. QKV projections
  gemm_bt<<<dim3(HID_/128, M/128), 256, 0, stream>>>(hsb, wqt, qlin, (int)M, HID_, HID_);
  gemm_bt<<<dim3(512/128,  M/128), 256, 0, stream>>>(hsb, wkt, klin, (int)M, 512, HID_);
  gemm_bt<<<dim3(512/128,  M/128), 256, 0, stream>>>(hsb, wvt, vbuf, (int)M, 512, HID_);
  // 6-7. RoPE + kappa (+ layout to [B,H,S,D])
  rope_kappa_q<<<(int)(M * NH_ * 32 / 256), 256, 0, stream>>>(qlin, qk);
  rope_kappa_k<<<(int)(M * NKV_ * 32 / 256), 256, 0, stream>>>(klin, kk);
  // 8. global query (split-S + atomics)
  hipMemsetAsync(qg, 0, 64 * 64 * 4, stream);
  qg_mean<<<dim3(B_ * NH_, S_ / 256), 256, 0, stream>>>(qk, qg);
  // 9. logits + softmax * S
  logits_kernel<<<dim3(B_ * NH_, S_ / 256), 256, 0, stream>>>(kk, qg, alph);
  softmax_kernel<<<B_ * NH_, 256, 0, stream>>>(alph, alph);
  // 10. outer_sum (zero-init + split-S atomics)
  hipMemsetAsync(osum, 0, (size_t)B_ * NH_ * 4096 * 4, stream);
  outer_sum_kernel<<<dim3(B_ * NH_, S_ / OS_CHUNK), 256, 0, stream>>>(kk, vbuf, alph, osum);
  // 11. Xphi projection (reuses qlin region)
  gemm_bt<<<dim3(HID_/128, M/128), 256, 0, stream>>>(hsb, wpt, qlin, (int)M, HID_, HID_);
  // 12. ctx = Xphi * (Qk @ osum)  -> bf16 (reuses klin+v region)
  ctx_kernel<<<dim3(B_ * NH_, S_ / 64), 256, 0, stream>>>(qk, osum, qlin, ctx);
  // 13. out = ctx @ Wo
  gemm_bt<<<dim3(HID_/128, M/128), 256, 0, stream>>>(ctx, wot, out, (int)M, HID_, HID_);
}

// Round 3
// 779.373 us; speedup vs baseline: 1.5475x; 1.2147x over previous
//
#include <hip/hip_runtime.h>
#include <hip/hip_bf16.h>

#define B_ 2
#define S_ 4096
#define HID_ 2048
#define NH_ 32
#define NKV_ 8
#define HD_ 64
#define GROUPS_ 4
#define NCH_ 32   // outer_sum S-chunks

typedef short short8 __attribute__((ext_vector_type(8)));
typedef float floatx4 __attribute__((ext_vector_type(4)));

__device__ __forceinline__ float bf2f(unsigned short u){
  union { unsigned int i; float f; } v; v.i = ((unsigned int)u) << 16; return v.f;
}
__device__ __forceinline__ unsigned short f2bf(float f){
  union { float f; unsigned int i; } v; v.f = f;
  unsigned int i = v.i;
  unsigned int r = (i + 0x7fffu + ((i >> 16) & 1u)) >> 16;  // RNE
  return (unsigned short)r;
}

// async global->LDS, 16B per lane, LDS dest = wave-uniform base + lane*16
__device__ __forceinline__ void async_copy16(unsigned short* lds, const unsigned short* g){
  __builtin_amdgcn_global_load_lds((const __attribute__((address_space(1))) void*)g,
                                   (__attribute__((address_space(3))) void*)lds,
                                   16, 0, 0);
}

// ---------------- fp32 -> bf16 bulk convert (hidden_states) ----------------
__global__ void conv_bf16(const float* __restrict__ x, unsigned short* __restrict__ y, int n4){
  int i = blockIdx.x * 256 + threadIdx.x;
  if (i < n4){
    float4 v = ((const float4*)x)[i];
    ushort4 o;
    o.x = f2bf(v.x); o.y = f2bf(v.y); o.z = f2bf(v.z); o.w = f2bf(v.w);
    ((ushort4*)y)[i] = o;
  }
}

// ---------------- W[K,N] fp32 -> Wt[N,K] bf16 (tiled transpose) ----------------
__global__ void transpose_to_bf16(const float* __restrict__ W, unsigned short* __restrict__ Wt,
                                  int K, int N){
  __shared__ float tile[32][33];
  int n0 = blockIdx.x * 32, k0 = blockIdx.y * 32;
  int tx = threadIdx.x, ty = threadIdx.y;   // 32 x 8
  #pragma unroll
  for (int j = 0; j < 4; j++)
    tile[ty + j*8][tx] = W[(size_t)(k0 + ty + j*8) * N + n0 + tx];
  __syncthreads();
  #pragma unroll
  for (int j = 0; j < 4; j++)
    Wt[(size_t)(n0 + ty + j*8) * K + k0 + tx] = f2bf(tile[tx][ty + j*8]);
}

// ---------------- C[M,N] fp32 = A[M,K] bf16 @ Bt[N,K]^T bf16 ----------------
// 128x128 tile, BK=32, 256 threads (4 waves), 4x4 mfma_16x16x32 per wave.
__global__ __launch_bounds__(256) void gemm_bt(
    const unsigned short* __restrict__ A, const unsigned short* __restrict__ Bt,
    float* __restrict__ C, int M, int N, int K)
{
  __shared__ __align__(16) unsigned short As[128 * 32];
  __shared__ __align__(16) unsigned short Bs[128 * 32];
  int tid = threadIdx.x;
  int m0 = blockIdx.y * 128, n0 = blockIdx.x * 128;
  int wave = tid >> 6, lane = tid & 63;
  int wm = (wave & 1) * 64, wn = (wave >> 1) * 64;
  int l15 = lane & 15, quad = lane >> 4;
  int lrow = lane >> 2, lcol = (lane & 3) * 8;   // staging: lane -> (row, col8)
  int wr0 = wave * 32;                           // wave's 32 staging rows

  const unsigned short* Ab = A  + (size_t)(m0 + wr0 + lrow) * K + lcol;
  const unsigned short* Bb = Bt + (size_t)(n0 + wr0 + lrow) * K + lcol;

  floatx4 acc[4][4] = {};

  for (int k0 = 0; k0 < K; k0 += 32){
    async_copy16(&As[(size_t)wr0 * 32],        Ab + k0);
    async_copy16(&As[(size_t)(wr0 + 16) * 32], Ab + (size_t)16 * K + k0);
    async_copy16(&Bs[(size_t)wr0 * 32],        Bb + k0);
    async_copy16(&Bs[(size_t)(wr0 + 16) * 32], Bb + (size_t)16 * K + k0);
    __syncthreads();
    short8 af[4], bfr[4];
    #pragma unroll
    for (int i = 0; i < 4; i++){
      af[i]  = *(const short8*)(&As[(wm + i*16 + l15) * 32 + quad * 8]);
      bfr[i] = *(const short8*)(&Bs[(wn + i*16 + l15) * 32 + quad * 8]);
    }
    #pragma unroll
    for (int mi = 0; mi < 4; mi++)
      #pragma unroll
      for (int ni = 0; ni < 4; ni++)
        acc[mi][ni] = __builtin_amdgcn_mfma_f32_16x16x32_bf16(af[mi], bfr[ni], acc[mi][ni], 0, 0, 0);
    __syncthreads();
  }

  #pragma unroll
  for (int mi = 0; mi < 4; mi++){
    int row = m0 + wm + mi*16 + quad*4;
    #pragma unroll
    for (int ni = 0; ni < 4; ni++){
      int col = n0 + wn + ni*16 + l15;
      #pragma unroll
      for (int r = 0; r < 4; r++)
        C[(size_t)(row + r) * N + col] = acc[mi][ni][r];
    }
  }
}

// ---------------- RoPE + kappa for Q: [B,S,NH,HD] fp32 -> [B,NH,S,HD] bf16 ----------------
__global__ void rope_kappa_q(const float* __restrict__ Qlin, unsigned short* __restrict__ Qk){
  int idx = blockIdx.x * 256 + threadIdx.x;    // B*S*NH*32 = 2^23 threads
  int i = idx & 31;
  int n = (idx >> 5) & (NH_ - 1);
  int s = (idx >> 10) & (S_ - 1);
  int b = idx >> 22;
  float invf = exp2f(-(float)i * (13.287712379549449f / 32.0f));  // 10000^(-i/32)
  float ang = (float)s * invf;
  float c = cosf(ang), sn = sinf(ang);
  size_t in_o = ((size_t)(b * S_ + s) * NH_ + n) * HD_;
  float x1 = Qlin[in_o + i];
  float x2 = Qlin[in_o + i + 32];
  float r1 = x1 * c - x2 * sn;
  float r2 = x2 * c + x1 * sn;
  r1 = r1 > 0.f ? r1 + 1.f : __expf(r1);
  r2 = r2 > 0.f ? r2 + 1.f : __expf(r2);
  size_t o = ((size_t)(b * NH_ + n) * S_ + s) * HD_;
  Qk[o + i] = f2bf(r1);
  Qk[o + i + 32] = f2bf(r2);
}

// ---------------- RoPE + kappa for K: [B,S,NKV,HD] fp32 -> [B,NKV,S,HD] bf16 ----------------
__global__ void rope_kappa_k(const float* __restrict__ Klin, unsigned short* __restrict__ Kk){
  int idx = blockIdx.x * 256 + threadIdx.x;    // B*S*NKV*32 = 2^21 threads
  int i = idx & 31;
  int kv = (idx >> 5) & (NKV_ - 1);
  int s = (idx >> 8) & (S_ - 1);
  int b = idx >> 20;
  float invf = exp2f(-(float)i * (13.287712379549449f / 32.0f));
  float ang = (float)s * invf;
  float c = cosf(ang), sn = sinf(ang);
  size_t in_o = ((size_t)(b * S_ + s) * NKV_ + kv) * HD_;
  float x1 = Klin[in_o + i];
  float x2 = Klin[in_o + i + 32];
  float r1 = x1 * c - x2 * sn;
  float r2 = x2 * c + x1 * sn;
  r1 = r1 > 0.f ? r1 + 1.f : __expf(r1);
  r2 = r2 > 0.f ? r2 + 1.f : __expf(r2);
  size_t o = ((size_t)(b * NKV_ + kv) * S_ + s) * HD_;
  Kk[o + i] = f2bf(r1);
  Kk[o + i + 32] = f2bf(r2);
}

// ---------------- Qg[b,n,d] = mean_s Qk[b,n,s,d]  (split-S, atomics) ----------------
__global__ __launch_bounds__(256) void qg_mean(const unsigned short* __restrict__ Qk,
                                               float* __restrict__ Qg){
  int bn = blockIdx.x, chunk = blockIdx.y;     // 64 x 16
  int tid = threadIdx.x;
  int dgrp = tid & 7, sgrp = tid >> 3;         // 8 d-chunks x 32 s-rows
  const unsigned short* base = Qk + (size_t)bn * S_ * HD_
                             + (size_t)(chunk * 256 + sgrp) * HD_ + dgrp * 8;
  float acc[8] = {};
  #pragma unroll
  for (int i = 0; i < 8; i++){
    short8 v = *(const short8*)(base + (size_t)i * 32 * HD_);
    #pragma unroll
    for (int e = 0; e < 8; e++) acc[e] += bf2f((unsigned short)v[e]);
  }
  __shared__ float red[256][8];
  #pragma unroll
  for (int e = 0; e < 8; e++) red[tid][e] = acc[e];
  __syncthreads();
  if (tid < 64){
    int dg = tid >> 3, e = tid & 7;
    float s = 0.f;
    #pragma unroll
    for (int g = 0; g < 32; g++) s += red[g * 8 + dg][e];
    atomicAdd(&Qg[bn * 64 + tid], s * (1.0f / (float)S_));
  }
}

// ---------------- logits[b,n,s] = dot(Qg[b,n], Kk[b,kv,s]) ----------------
__global__ __launch_bounds__(256) void logits_kernel(const unsigned short* __restrict__ Kk,
                                                     const float* __restrict__ Qg,
                                                     float* __restrict__ logits){
  int bn = blockIdx.x, chunk = blockIdx.y;     // 64 x 16
  int b = bn / NH_, n = bn % NH_, kv = n / GROUPS_;
  int tid = threadIdx.x;
  __shared__ float qg[64];
  if (tid < 64) qg[tid] = Qg[bn * 64 + tid];
  __syncthreads();
  int s = chunk * 256 + tid;
  const unsigned short* row = Kk + ((size_t)(b * NKV_ + kv) * S_ + s) * HD_;
  float acc = 0.f;
  #pragma unroll
  for (int c = 0; c < 8; c++){
    short8 v = *(const short8*)(row + c * 8);
    #pragma unroll
    for (int e = 0; e < 8; e++) acc += qg[c * 8 + e] * bf2f((unsigned short)v[e]);
  }
  logits[(size_t)bn * S_ + s] = acc;
}

// ---------------- softmax * S over logits -> alpha (in place OK) ----------------
__global__ __launch_bounds__(256) void softmax_kernel(const float* __restrict__ logits,
                                                      float* __restrict__ alpha){
  int bn = blockIdx.x;
  int tid = threadIdx.x;
  float l[16];
  float mymax = -1e30f;
  #pragma unroll
  for (int j = 0; j < 16; j++){
    l[j] = logits[(size_t)bn * S_ + j * 256 + tid];
    mymax = fmaxf(mymax, l[j]);
  }
  __shared__ float red[256];
  red[tid] = mymax; __syncthreads();
  for (int st = 128; st > 0; st >>= 1){
    if (tid < st) red[tid] = fmaxf(red[tid], red[tid + st]);
    __syncthreads();
  }
  float gmax = red[0];
  __syncthreads();
  float mysum = 0.f;
  #pragma unroll
  for (int j = 0; j < 16; j++){ l[j] = __expf(l[j] - gmax); mysum += l[j]; }
  red[tid] = mysum; __syncthreads();
  for (int st = 128; st > 0; st >>= 1){
    if (tid < st) red[tid] += red[tid + st];
    __syncthreads();
  }
  float inv = (float)S_ / red[0];
  #pragma unroll
  for (int j = 0; j < 16; j++)
    alpha[(size_t)bn * S_ + j * 256 + tid] = l[j] * inv;
}

// ---------------- outer_sum v2: per (b,kv,chunk), all 4 GQA heads at once ----------------
// part[chunk][bkv][h][d*64+f] partial sums; atomic-free.
__global__ __launch_bounds__(256) void outer_sum_kernel(const unsigned short* __restrict__ Kk,
                                                        const float* __restrict__ V,
                                                        const float* __restrict__ alpha,
                                                        float* __restrict__ part){
  int bkv = blockIdx.x, chunk = blockIdx.y;     // 16 x NCH_
  int b = bkv >> 3, kv = bkv & 7;
  int tid = threadIdx.x;
  int d = tid >> 2, fb = (tid & 3) * 16;
  __shared__ float ks[64][64];   // [si][d]
  __shared__ float vs[64][64];   // [si][f]
  __shared__ float as[4][64];    // [h][si]
  float acc[4][16] = {};
  const unsigned short* kb = Kk + (size_t)(b * NKV_ + kv) * S_ * HD_;
  const int SPC = S_ / NCH_;     // 128 s per chunk

  for (int t = 0; t < SPC / 64; t++){
    int ss = chunk * SPC + t * 64;
    #pragma unroll
    for (int j = 0; j < 16; j++){
      int idx = j * 256 + tid;
      int si = idx >> 6, dd = idx & 63;
      ks[si][dd] = bf2f(kb[(size_t)(ss + si) * HD_ + dd]);
      vs[si][dd] = V[((size_t)(b * S_ + ss + si) * NKV_ + kv) * HD_ + dd];
    }
    {
      int h = tid >> 6, si = tid & 63;
      as[h][si] = alpha[(size_t)(b * NH_ + kv * GROUPS_ + h) * S_ + ss + si];
    }
    __syncthreads();
    #pragma unroll 4
    for (int si = 0; si < 64; si++){
      float k = ks[si][d];
      float4 v0 = *(const float4*)&vs[si][fb];
      float4 v1 = *(const float4*)&vs[si][fb + 4];
      float4 v2 = *(const float4*)&vs[si][fb + 8];
      float4 v3 = *(const float4*)&vs[si][fb + 12];
      #pragma unroll
      for (int h = 0; h < 4; h++){
        float ak = as[h][si] * k;
        acc[h][0]  += ak * v0.x; acc[h][1]  += ak * v0.y; acc[h][2]  += ak * v0.z; acc[h][3]  += ak * v0.w;
        acc[h][4]  += ak * v1.x; acc[h][5]  += ak * v1.y; acc[h][6]  += ak * v1.z; acc[h][7]  += ak * v1.w;
        acc[h][8]  += ak * v2.x; acc[h][9]  += ak * v2.y; acc[h][10] += ak * v2.z; acc[h][11] += ak * v2.w;
        acc[h][12] += ak * v3.x; acc[h][13] += ak * v3.y; acc[h][14] += ak * v3.z; acc[h][15] += ak * v3.w;
      }
    }
    __syncthreads();
  }

  #pragma unroll
  for (int h = 0; h < 4; h++){
    float* pb = part + ((size_t)(chunk * 16 + bkv) * 4 + h) * 4096 + d * 64 + fb;
    #pragma unroll
    for (int j = 0; j < 4; j++)
      *(float4*)&pb[j * 4] = *(float4*)&acc[h][j * 4];
  }
}

// ---------------- reduce partials over NCH_ chunks -> osum[bn][d*64+f] ----------------
__global__ __launch_bounds__(256) void osum_reduce(const float* __restrict__ part,
                                                   float* __restrict__ osum){
  int i = blockIdx.x * 256 + threadIdx.x;   // over 64*4096/4 = 65536 float4
  float4 s = {0.f, 0.f, 0.f, 0.f};
  #pragma unroll 8
  for (int c = 0; c < NCH_; c++){
    float4 v = ((const float4*)part)[(size_t)c * 65536 + i];
    s.x += v.x; s.y += v.y; s.z += v.z; s.w += v.w;
  }
  ((float4*)osum)[i] = s;
}

// ---------------- ctx[b,s,n*64+f] = Xphi[b,s,n,f] * sum_d Qk[b,n,s,d]*osum[b,n,d,f] ----------------
__global__ __launch_bounds__(256) void ctx_kernel(const unsigned short* __restrict__ Qk,
                                                  const float* __restrict__ osum,
                                                  const float* __restrict__ Xphi,
                                                  unsigned short* __restrict__ ctx){
  int bn = blockIdx.x, sc = blockIdx.y;
  int b = bn / NH_, n = bn % NH_;
  int tid = threadIdx.x;
  __shared__ float os[64][65];
  __shared__ float qs[64][65];
  #pragma unroll
  for (int j = 0; j < 16; j++){
    int idx = j * 256 + tid;
    int r = idx >> 6, cix = idx & 63;
    os[r][cix] = osum[(size_t)bn * 4096 + idx];
    qs[r][cix] = bf2f(Qk[((size_t)bn * S_ + sc * 64 + r) * HD_ + cix]);
  }
  __syncthreads();
  int sl = tid >> 2, fb = (tid & 3) * 16;
  float r[16] = {};
  #pragma unroll 8
  for (int d = 0; d < 64; d++){
    float q = qs[sl][d];
    #pragma unroll
    for (int j = 0; j < 16; j++) r[j] += q * os[d][fb + j];
  }
  int s = sc * 64 + sl;
  const float* xp = Xphi + ((size_t)(b * S_ + s) * NH_ + n) * HD_ + fb;
  unsigned short* cp = ctx + (size_t)(b * S_ + s) * HID_ + n * HD_ + fb;
  #pragma unroll
  for (int j = 0; j < 16; j++) cp[j] = f2bf(xp[j] * r[j]);
}

extern "C" void kernel_launch(void* const* d_in, const int* in_sizes, int n_in,
                              void* d_out, int out_size, void* d_ws, size_t ws_size,
                              hipStream_t stream) {
  const float* hs   = (const float*)d_in[0];
  const float* Wq   = (const float*)d_in[1];
  const float* Wk   = (const float*)d_in[2];
  const float* Wv   = (const float*)d_in[3];
  const float* Wphi = (const float*)d_in[4];
  const float* Wo   = (const float*)d_in[5];
  float* out = (float*)d_out;

  char* ws = (char*)d_ws;
  const size_t M = (size_t)B_ * S_;          // 8192
  size_t off = 0;
  auto alloc = [&](size_t bytes){ size_t o = off; off += (bytes + 255) & ~(size_t)255; return o; };

  size_t off_hsb  = alloc(M * HID_ * 2);                 // 32MB bf16
  size_t off_wqt  = alloc((size_t)HID_ * HID_ * 2);      // 8MB
  size_t off_wkt  = alloc((size_t)HID_ * 512 * 2);       // 2MB
  size_t off_wvt  = alloc((size_t)HID_ * 512 * 2);       // 2MB
  size_t off_wpt  = alloc((size_t)HID_ * HID_ * 2);      // 8MB
  size_t off_wot  = alloc((size_t)HID_ * HID_ * 2);      // 8MB
  size_t off_qlin = alloc(M * HID_ * 4);                 // 64MB fp32 (Xphi later; osum partials in between)
  size_t off_klin = alloc(M * 512 * 4);                  // 16MB fp32
  size_t off_v    = alloc(M * 512 * 4);                  // 16MB fp32
  size_t off_qk   = alloc(M * HID_ * 2);                 // 32MB bf16 [B,NH,S,D]
  size_t off_kk   = alloc(M * 512 * 2);                  // 8MB  bf16 [B,NKV,S,D]
  size_t off_qg   = alloc(64 * 64 * 4);
  size_t off_alph = alloc((size_t)B_ * NH_ * S_ * 4);    // 1MB
  size_t off_osum = alloc((size_t)B_ * NH_ * 4096 * 4);  // 1MB
  size_t off_ctx  = off_klin;                            // reuse klin+v region (32MB bf16)
  size_t off_part = off_qlin;                            // 32MB partials, reuses dead qlin window
  (void)ws_size;

  unsigned short* hsb = (unsigned short*)(ws + off_hsb);
  unsigned short* wqt = (unsigned short*)(ws + off_wqt);
  unsigned short* wkt = (unsigned short*)(ws + off_wkt);
  unsigned short* wvt = (unsigned short*)(ws + off_wvt);
  unsigned short* wpt = (unsigned short*)(ws + off_wpt);
  unsigned short* wot = (unsigned short*)(ws + off_wot);
  float* qlin = (float*)(ws + off_qlin);
  float* klin = (float*)(ws + off_klin);
  float* vbuf = (float*)(ws + off_v);
  unsigned short* qk = (unsigned short*)(ws + off_qk);
  unsigned short* kk = (unsigned short*)(ws + off_kk);
  float* qg   = (float*)(ws + off_qg);
  float* alph = (float*)(ws + off_alph);
  float* osum = (float*)(ws + off_osum);
  float* part = (float*)(ws + off_part);
  unsigned short* ctx = (unsigned short*)(ws + off_ctx);

  // 1. hs -> bf16
  conv_bf16<<<(int)(M * HID_ / 4 / 256), 256, 0, stream>>>(hs, hsb, (int)(M * HID_ / 4));
  // 2. weight transposes (W[K,N] -> Wt[N,K] bf16)
  transpose_to_bf16<<<dim3(HID_/32, HID_/32), dim3(32,8), 0, stream>>>(Wq, wqt, HID_, HID_);
  transpose_to_bf16<<<dim3(512/32,  HID_/32), dim3(32,8), 0, stream>>>(Wk, wkt, HID_, 512);
  transpose_to_bf16<<<dim3(512/32,  HID_/32), dim3(32,8), 0, stream>>>(Wv, wvt, HID_, 512);
  transpose_to_bf16<<<dim3(HID_/32, HID_/32), dim3(32,8), 0, stream>>>(Wphi, wpt, HID_, HID_);
  transpose_to_bf16<<<dim3(HID_/32, HID_/32), dim3(32,8), 0, stream>>>(Wo, wot, HID_, HID_);
  // 3-5. QKV projections
  gemm_bt<<<dim3(HID_/128, M/128), 256, 0, stream>>>(hsb, wqt, qlin, (int)M, HID_, HID_);
  gemm_bt<<<dim3(512/128,  M/128), 256, 0, stream>>>(hsb, wkt, klin, (int)M, 512, HID_);
  gemm_bt<<<dim3(512/128,  M/128), 256, 0, stream>>>(hsb, wvt, vbuf, (int)M, 512, HID_);
  // 6-7. RoPE + kappa (+ layout to [B,H,S,D])
  rope_kappa_q<<<(int)(M * NH_ * 32 / 256), 256, 0, stream>>>(qlin, qk);
  rope_kappa_k<<<(int)(M * NKV_ * 32 / 256), 256, 0, stream>>>(klin, kk);
  // 8. global query (split-S + atomics)
  hipMemsetAsync(qg, 0, 64 * 64 * 4, stream);
  qg_mean<<<dim3(B_ * NH_, S_ / 256), 256, 0, stream>>>(qk, qg);
  // 9. logits + softmax * S
  logits_kernel<<<dim3(B_ * NH_, S_ / 256), 256, 0, stream>>>(kk, qg, alph);
  softmax_kernel<<<B_ * NH_, 256, 0, stream>>>(alph, alph);
  // 10. outer_sum v2 (GQA-grouped, atomic-free partials into dead qlin region) + reduce
  outer_sum_kernel<<<dim3(B_ * NKV_, NCH_), 256, 0, stream>>>(kk, vbuf, alph, part);
  osum_reduce<<<256, 256, 0, stream>>>(part, osum);
  // 11. Xphi projection (reuses qlin region — partials dead after reduce)
  gemm_bt<<<dim3(HID_/128, M/128), 256, 0, stream>>>(hsb, wpt, qlin, (int)M, HID_, HID_);
  // 12. ctx = Xphi * (Qk @ osum)  -> bf16 (reuses klin+v region)
  ctx_kernel<<<dim3(B_ * NH_, S_ / 64), 256, 0, stream>>>(qk, osum, qlin, ctx);
  // 13. out = ctx @ Wo
  gemm_bt<<<dim3(HID_/128, M/128), 256, 0, stream>>>(ctx, wot, out, (int)M, HID_, HID_);
}

// Round 4
// 737.726 us; speedup vs baseline: 1.6349x; 1.0565x over previous
//
#include <hip/hip_runtime.h>
#include <hip/hip_bf16.h>

#define B_ 2
#define S_ 4096
#define HID_ 2048
#define NH_ 32
#define NKV_ 8
#define HD_ 64
#define GROUPS_ 4
#define NCH_ 32   // outer_sum S-chunks

typedef short short8 __attribute__((ext_vector_type(8)));
typedef float floatx4 __attribute__((ext_vector_type(4)));

__device__ __forceinline__ float bf2f(unsigned short u){
  union { unsigned int i; float f; } v; v.i = ((unsigned int)u) << 16; return v.f;
}
__device__ __forceinline__ unsigned short f2bf(float f){
  union { float f; unsigned int i; } v; v.f = f;
  unsigned int i = v.i;
  unsigned int r = (i + 0x7fffu + ((i >> 16) & 1u)) >> 16;  // RNE
  return (unsigned short)r;
}

// async global->LDS, 16B per lane, LDS dest = wave-uniform base + lane*16
__device__ __forceinline__ void async_copy16(unsigned short* lds, const unsigned short* g){
  __builtin_amdgcn_global_load_lds((const __attribute__((address_space(1))) void*)g,
                                   (__attribute__((address_space(3))) void*)lds,
                                   16, 0, 0);
}

// ---------------- fp32 -> bf16 bulk convert (hidden_states) ----------------
__global__ void conv_bf16(const float* __restrict__ x, unsigned short* __restrict__ y, int n4){
  int i = blockIdx.x * 256 + threadIdx.x;
  if (i < n4){
    float4 v = ((const float4*)x)[i];
    ushort4 o;
    o.x = f2bf(v.x); o.y = f2bf(v.y); o.z = f2bf(v.z); o.w = f2bf(v.w);
    ((ushort4*)y)[i] = o;
  }
}

// ---------------- W[K,N] fp32 -> Wt[N,K] bf16 (tiled transpose) ----------------
__global__ void transpose_to_bf16(const float* __restrict__ W, unsigned short* __restrict__ Wt,
                                  int K, int N){
  __shared__ float tile[32][33];
  int n0 = blockIdx.x * 32, k0 = blockIdx.y * 32;
  int tx = threadIdx.x, ty = threadIdx.y;   // 32 x 8
  #pragma unroll
  for (int j = 0; j < 4; j++)
    tile[ty + j*8][tx] = W[(size_t)(k0 + ty + j*8) * N + n0 + tx];
  __syncthreads();
  #pragma unroll
  for (int j = 0; j < 4; j++)
    Wt[(size_t)(n0 + ty + j*8) * K + k0 + tx] = f2bf(tile[tx][ty + j*8]);
}

// ---------------- C[M,N] fp32 = A[M,K] bf16 @ Bt[N,K]^T bf16 ----------------
// 128x128 tile, BK=32, 256 threads (4 waves), 4x4 mfma_16x16x32 per wave.
// XOR-swizzled LDS: 16B chunk c of row r lives at LDS chunk r*4 + (c ^ ((r>>1)&3)).
// Staging lanes fetch the permuted chunk (same 64B row -> coalescing preserved);
// frag reads apply the same XOR -> each quarter-wave spreads over all 8 bank groups.
__global__ __launch_bounds__(256) void gemm_bt(
    const unsigned short* __restrict__ A, const unsigned short* __restrict__ Bt,
    float* __restrict__ C, int M, int N, int K)
{
  __shared__ __align__(16) unsigned short As[128 * 32];
  __shared__ __align__(16) unsigned short Bs[128 * 32];
  int tid = threadIdx.x;
  int m0 = blockIdx.y * 128, n0 = blockIdx.x * 128;
  int wave = tid >> 6, lane = tid & 63;
  int wm = (wave & 1) * 64, wn = (wave >> 1) * 64;
  int l15 = lane & 15, quad = lane >> 4;
  int wr0 = wave * 32;                           // wave's 32 staging rows

  // staging: copy j covers tile rows [wr0+j*16, wr0+j*16+16); lane -> (row, slot)
  int sr0 = wr0 + (lane >> 2);                   // row for copy 0
  int sr1 = sr0 + 16;                            // row for copy 1
  int cs  = lane & 3;                            // LDS slot chunk
  int cg0 = cs ^ ((sr0 >> 1) & 3);               // global chunk to fetch
  int cg1 = cs ^ ((sr1 >> 1) & 3);

  const unsigned short* Ab0 = A  + (size_t)(m0 + sr0) * K + cg0 * 8;
  const unsigned short* Ab1 = A  + (size_t)(m0 + sr1) * K + cg1 * 8;
  const unsigned short* Bb0 = Bt + (size_t)(n0 + sr0) * K + cg0 * 8;
  const unsigned short* Bb1 = Bt + (size_t)(n0 + sr1) * K + cg1 * 8;

  // frag read offsets (shorts), constant over K-loop
  int aoff[4], boff[4];
  #pragma unroll
  for (int i = 0; i < 4; i++){
    int ra = wm + i*16 + l15;
    aoff[i] = ra * 32 + ((quad ^ ((ra >> 1) & 3)) * 8);
    int rb = wn + i*16 + l15;
    boff[i] = rb * 32 + ((quad ^ ((rb >> 1) & 3)) * 8);
  }

  floatx4 acc[4][4] = {};

  for (int k0 = 0; k0 < K; k0 += 32){
    async_copy16(&As[(size_t)wr0 * 32],        Ab0 + k0);
    async_copy16(&As[(size_t)(wr0 + 16) * 32], Ab1 + k0);
    async_copy16(&Bs[(size_t)wr0 * 32],        Bb0 + k0);
    async_copy16(&Bs[(size_t)(wr0 + 16) * 32], Bb1 + k0);
    __syncthreads();
    short8 af[4], bfr[4];
    #pragma unroll
    for (int i = 0; i < 4; i++){
      af[i]  = *(const short8*)(&As[aoff[i]]);
      bfr[i] = *(const short8*)(&Bs[boff[i]]);
    }
    #pragma unroll
    for (int mi = 0; mi < 4; mi++)
      #pragma unroll
      for (int ni = 0; ni < 4; ni++)
        acc[mi][ni] = __builtin_amdgcn_mfma_f32_16x16x32_bf16(af[mi], bfr[ni], acc[mi][ni], 0, 0, 0);
    __syncthreads();
  }

  #pragma unroll
  for (int mi = 0; mi < 4; mi++){
    int row = m0 + wm + mi*16 + quad*4;
    #pragma unroll
    for (int ni = 0; ni < 4; ni++){
      int col = n0 + wn + ni*16 + l15;
      #pragma unroll
      for (int r = 0; r < 4; r++)
        C[(size_t)(row + r) * N + col] = acc[mi][ni][r];
    }
  }
}

// ---------------- RoPE + kappa for Q: [B,S,NH,HD] fp32 -> [B,NH,S,HD] bf16 ----------------
__global__ void rope_kappa_q(const float* __restrict__ Qlin, unsigned short* __restrict__ Qk){
  int idx = blockIdx.x * 256 + threadIdx.x;    // B*S*NH*32 = 2^23 threads
  int i = idx & 31;
  int n = (idx >> 5) & (NH_ - 1);
  int s = (idx >> 10) & (S_ - 1);
  int b = idx >> 22;
  float invf = exp2f(-(float)i * (13.287712379549449f / 32.0f));  // 10000^(-i/32)
  float ang = (float)s * invf;
  float c = cosf(ang), sn = sinf(ang);
  size_t in_o = ((size_t)(b * S_ + s) * NH_ + n) * HD_;
  float x1 = Qlin[in_o + i];
  float x2 = Qlin[in_o + i + 32];
  float r1 = x1 * c - x2 * sn;
  float r2 = x2 * c + x1 * sn;
  r1 = r1 > 0.f ? r1 + 1.f : __expf(r1);
  r2 = r2 > 0.f ? r2 + 1.f : __expf(r2);
  size_t o = ((size_t)(b * NH_ + n) * S_ + s) * HD_;
  Qk[o + i] = f2bf(r1);
  Qk[o + i + 32] = f2bf(r2);
}

// ---------------- RoPE + kappa for K (fused KV layout [B,S,1024], K = cols 0..511) ----------------
__global__ void rope_kappa_k(const float* __restrict__ KVlin, unsigned short* __restrict__ Kk){
  int idx = blockIdx.x * 256 + threadIdx.x;    // B*S*NKV*32 = 2^21 threads
  int i = idx & 31;
  int kv = (idx >> 5) & (NKV_ - 1);
  int s = (idx >> 8) & (S_ - 1);
  int b = idx >> 20;
  float invf = exp2f(-(float)i * (13.287712379549449f / 32.0f));
  float ang = (float)s * invf;
  float c = cosf(ang), sn = sinf(ang);
  size_t in_o = (size_t)(b * S_ + s) * 1024 + kv * HD_;
  float x1 = KVlin[in_o + i];
  float x2 = KVlin[in_o + i + 32];
  float r1 = x1 * c - x2 * sn;
  float r2 = x2 * c + x1 * sn;
  r1 = r1 > 0.f ? r1 + 1.f : __expf(r1);
  r2 = r2 > 0.f ? r2 + 1.f : __expf(r2);
  size_t o = ((size_t)(b * NKV_ + kv) * S_ + s) * HD_;
  Kk[o + i] = f2bf(r1);
  Kk[o + i + 32] = f2bf(r2);
}

// ---------------- Qg[b,n,d] = mean_s Qk[b,n,s,d]  (split-S, atomics) ----------------
__global__ __launch_bounds__(256) void qg_mean(const unsigned short* __restrict__ Qk,
                                               float* __restrict__ Qg){
  int bn = blockIdx.x, chunk = blockIdx.y;     // 64 x 16
  int tid = threadIdx.x;
  int dgrp = tid & 7, sgrp = tid >> 3;         // 8 d-chunks x 32 s-rows
  const unsigned short* base = Qk + (size_t)bn * S_ * HD_
                             + (size_t)(chunk * 256 + sgrp) * HD_ + dgrp * 8;
  float acc[8] = {};
  #pragma unroll
  for (int i = 0; i < 8; i++){
    short8 v = *(const short8*)(base + (size_t)i * 32 * HD_);
    #pragma unroll
    for (int e = 0; e < 8; e++) acc[e] += bf2f((unsigned short)v[e]);
  }
  __shared__ float red[256][8];
  #pragma unroll
  for (int e = 0; e < 8; e++) red[tid][e] = acc[e];
  __syncthreads();
  if (tid < 64){
    int dg = tid >> 3, e = tid & 7;
    float s = 0.f;
    #pragma unroll
    for (int g = 0; g < 32; g++) s += red[g * 8 + dg][e];
    atomicAdd(&Qg[bn * 64 + tid], s * (1.0f / (float)S_));
  }
}

// ---------------- logits[b,n,s] = dot(Qg[b,n], Kk[b,kv,s]) ----------------
__global__ __launch_bounds__(256) void logits_kernel(const unsigned short* __restrict__ Kk,
                                                     const float* __restrict__ Qg,
                                                     float* __restrict__ logits){
  int bn = blockIdx.x, chunk = blockIdx.y;     // 64 x 16
  int b = bn / NH_, n = bn % NH_, kv = n / GROUPS_;
  int tid = threadIdx.x;
  __shared__ float qg[64];
  if (tid < 64) qg[tid] = Qg[bn * 64 + tid];
  __syncthreads();
  int s = chunk * 256 + tid;
  const unsigned short* row = Kk + ((size_t)(b * NKV_ + kv) * S_ + s) * HD_;
  float acc = 0.f;
  #pragma unroll
  for (int c = 0; c < 8; c++){
    short8 v = *(const short8*)(row + c * 8);
    #pragma unroll
    for (int e = 0; e < 8; e++) acc += qg[c * 8 + e] * bf2f((unsigned short)v[e]);
  }
  logits[(size_t)bn * S_ + s] = acc;
}

// ---------------- softmax * S over logits -> alpha (in place OK) ----------------
__global__ __launch_bounds__(256) void softmax_kernel(const float* __restrict__ logits,
                                                      float* __restrict__ alpha){
  int bn = blockIdx.x;
  int tid = threadIdx.x;
  float l[16];
  float mymax = -1e30f;
  #pragma unroll
  for (int j = 0; j < 16; j++){
    l[j] = logits[(size_t)bn * S_ + j * 256 + tid];
    mymax = fmaxf(mymax, l[j]);
  }
  __shared__ float red[256];
  red[tid] = mymax; __syncthreads();
  for (int st = 128; st > 0; st >>= 1){
    if (tid < st) red[tid] = fmaxf(red[tid], red[tid + st]);
    __syncthreads();
  }
  float gmax = red[0];
  __syncthreads();
  float mysum = 0.f;
  #pragma unroll
  for (int j = 0; j < 16; j++){ l[j] = __expf(l[j] - gmax); mysum += l[j]; }
  red[tid] = mysum; __syncthreads();
  for (int st = 128; st > 0; st >>= 1){
    if (tid < st) red[tid] += red[tid + st];
    __syncthreads();
  }
  float inv = (float)S_ / red[0];
  #pragma unroll
  for (int j = 0; j < 16; j++)
    alpha[(size_t)bn * S_ + j * 256 + tid] = l[j] * inv;
}

// ---------------- outer_sum: per (b,kv,chunk), all 4 GQA heads; V from fused KV cols 512.. ----------------
__global__ __launch_bounds__(256) void outer_sum_kernel(const unsigned short* __restrict__ Kk,
                                                        const float* __restrict__ KVlin,
                                                        const float* __restrict__ alpha,
                                                        float* __restrict__ part){
  int bkv = blockIdx.x, chunk = blockIdx.y;     // 16 x NCH_
  int b = bkv >> 3, kv = bkv & 7;
  int tid = threadIdx.x;
  int d = tid >> 2, fb = (tid & 3) * 16;
  __shared__ float ks[64][64];   // [si][d]
  __shared__ float vs[64][64];   // [si][f]
  __shared__ float as[4][64];    // [h][si]
  float acc[4][16] = {};
  const unsigned short* kb = Kk + (size_t)(b * NKV_ + kv) * S_ * HD_;
  const int SPC = S_ / NCH_;     // 128 s per chunk

  for (int t = 0; t < SPC / 64; t++){
    int ss = chunk * SPC + t * 64;
    #pragma unroll
    for (int j = 0; j < 16; j++){
      int idx = j * 256 + tid;
      int si = idx >> 6, dd = idx & 63;
      ks[si][dd] = bf2f(kb[(size_t)(ss + si) * HD_ + dd]);
      vs[si][dd] = KVlin[(size_t)(b * S_ + ss + si) * 1024 + 512 + kv * HD_ + dd];
    }
    {
      int h = tid >> 6, si = tid & 63;
      as[h][si] = alpha[(size_t)(b * NH_ + kv * GROUPS_ + h) * S_ + ss + si];
    }
    __syncthreads();
    #pragma unroll 4
    for (int si = 0; si < 64; si++){
      float k = ks[si][d];
      float4 v0 = *(const float4*)&vs[si][fb];
      float4 v1 = *(const float4*)&vs[si][fb + 4];
      float4 v2 = *(const float4*)&vs[si][fb + 8];
      float4 v3 = *(const float4*)&vs[si][fb + 12];
      #pragma unroll
      for (int h = 0; h < 4; h++){
        float ak = as[h][si] * k;
        acc[h][0]  += ak * v0.x; acc[h][1]  += ak * v0.y; acc[h][2]  += ak * v0.z; acc[h][3]  += ak * v0.w;
        acc[h][4]  += ak * v1.x; acc[h][5]  += ak * v1.y; acc[h][6]  += ak * v1.z; acc[h][7]  += ak * v1.w;
        acc[h][8]  += ak * v2.x; acc[h][9]  += ak * v2.y; acc[h][10] += ak * v2.z; acc[h][11] += ak * v2.w;
        acc[h][12] += ak * v3.x; acc[h][13] += ak * v3.y; acc[h][14] += ak * v3.z; acc[h][15] += ak * v3.w;
      }
    }
    __syncthreads();
  }

  #pragma unroll
  for (int h = 0; h < 4; h++){
    float* pb = part + ((size_t)(chunk * 16 + bkv) * 4 + h) * 4096 + d * 64 + fb;
    #pragma unroll
    for (int j = 0; j < 4; j++)
      *(float4*)&pb[j * 4] = *(float4*)&acc[h][j * 4];
  }
}

// ---------------- reduce partials over NCH_ chunks -> osum[bn][d*64+f] ----------------
__global__ __launch_bounds__(256) void osum_reduce(const float* __restrict__ part,
                                                   float* __restrict__ osum){
  int i = blockIdx.x * 256 + threadIdx.x;   // over 64*4096/4 = 65536 float4
  float4 s = {0.f, 0.f, 0.f, 0.f};
  #pragma unroll 8
  for (int c = 0; c < NCH_; c++){
    float4 v = ((const float4*)part)[(size_t)c * 65536 + i];
    s.x += v.x; s.y += v.y; s.z += v.z; s.w += v.w;
  }
  ((float4*)osum)[i] = s;
}

// ---------------- ctx[b,s,n*64+f] = Xphi[b,s,n,f] * sum_d Qk[b,n,s,d]*osum[b,n,d,f] ----------------
__global__ __launch_bounds__(256) void ctx_kernel(const unsigned short* __restrict__ Qk,
                                                  const float* __restrict__ osum,
                                                  const float* __restrict__ Xphi,
                                                  unsigned short* __restrict__ ctx){
  int bn = blockIdx.x, sc = blockIdx.y;
  int b = bn / NH_, n = bn % NH_;
  int tid = threadIdx.x;
  __shared__ float os[64][65];
  __shared__ float qs[64][65];
  #pragma unroll
  for (int j = 0; j < 16; j++){
    int idx = j * 256 + tid;
    int r = idx >> 6, cix = idx & 63;
    os[r][cix] = osum[(size_t)bn * 4096 + idx];
    qs[r][cix] = bf2f(Qk[((size_t)bn * S_ + sc * 64 + r) * HD_ + cix]);
  }
  __syncthreads();
  int sl = tid >> 2, fb = (tid & 3) * 16;
  float r[16] = {};
  #pragma unroll 8
  for (int d = 0; d < 64; d++){
    float q = qs[sl][d];
    #pragma unroll
    for (int j = 0; j < 16; j++) r[j] += q * os[d][fb + j];
  }
  int s = sc * 64 + sl;
  const float* xp = Xphi + ((size_t)(b * S_ + s) * NH_ + n) * HD_ + fb;
  unsigned short* cp = ctx + (size_t)(b * S_ + s) * HID_ + n * HD_ + fb;
  #pragma unroll
  for (int j = 0; j < 16; j++) cp[j] = f2bf(xp[j] * r[j]);
}

extern "C" void kernel_launch(void* const* d_in, const int* in_sizes, int n_in,
                              void* d_out, int out_size, void* d_ws, size_t ws_size,
                              hipStream_t stream) {
  const float* hs   = (const float*)d_in[0];
  const float* Wq   = (const float*)d_in[1];
  const float* Wk   = (const float*)d_in[2];
  const float* Wv   = (const float*)d_in[3];
  const float* Wphi = (const float*)d_in[4];
  const float* Wo   = (const float*)d_in[5];
  float* out = (float*)d_out;

  char* ws = (char*)d_ws;
  const size_t M = (size_t)B_ * S_;          // 8192
  size_t off = 0;
  auto alloc = [&](size_t bytes){ size_t o = off; off += (bytes + 255) & ~(size_t)255; return o; };

  size_t off_hsb   = alloc(M * HID_ * 2);                 // 32MB bf16
  size_t off_wqt   = alloc((size_t)HID_ * HID_ * 2);      // 8MB
  size_t off_wkvt  = alloc((size_t)HID_ * 1024 * 2);      // 4MB  [Wk^T; Wv^T]
  size_t off_wpt   = alloc((size_t)HID_ * HID_ * 2);      // 8MB
  size_t off_wot   = alloc((size_t)HID_ * HID_ * 2);      // 8MB
  size_t off_qlin  = alloc(M * HID_ * 4);                 // 64MB fp32 (Xphi later; osum partials between)
  size_t off_kvlin = alloc(M * 1024 * 4);                 // 32MB fp32 fused K|V
  size_t off_qk    = alloc(M * HID_ * 2);                 // 32MB bf16 [B,NH,S,D]
  size_t off_kk    = alloc(M * 512 * 2);                  // 8MB  bf16 [B,NKV,S,D]
  size_t off_qg    = alloc(64 * 64 * 4);
  size_t off_alph  = alloc((size_t)B_ * NH_ * S_ * 4);    // 1MB
  size_t off_osum  = alloc((size_t)B_ * NH_ * 4096 * 4);  // 1MB
  size_t off_ctx   = off_kvlin;                           // reuse kvlin region (32MB bf16)
  size_t off_part  = off_qlin;                            // 32MB partials in dead qlin window
  (void)ws_size;

  unsigned short* hsb  = (unsigned short*)(ws + off_hsb);
  unsigned short* wqt  = (unsigned short*)(ws + off_wqt);
  unsigned short* wkvt = (unsigned short*)(ws + off_wkvt);
  unsigned short* wpt  = (unsigned short*)(ws + off_wpt);
  unsigned short* wot  = (unsigned short*)(ws + off_wot);
  float* qlin  = (float*)(ws + off_qlin);
  float* kvlin = (float*)(ws + off_kvlin);
  unsigned short* qk = (unsigned short*)(ws + off_qk);
  unsigned short* kk = (unsigned short*)(ws + off_kk);
  float* qg   = (float*)(ws + off_qg);
  float* alph = (float*)(ws + off_alph);
  float* osum = (float*)(ws + off_osum);
  float* part = (float*)(ws + off_part);
  unsigned short* ctx = (unsigned short*)(ws + off_ctx);

  // 1. hs -> bf16
  conv_bf16<<<(int)(M * HID_ / 4 / 256), 256, 0, stream>>>(hs, hsb, (int)(M * HID_ / 4));
  // 2. weight transposes (W[K,N] -> Wt[N,K] bf16); Wk/Wv concatenated
  transpose_to_bf16<<<dim3(HID_/32, HID_/32), dim3(32,8), 0, stream>>>(Wq, wqt, HID_, HID_);
  transpose_to_bf16<<<dim3(512/32,  HID_/32), dim3(32,8), 0, stream>>>(Wk, wkvt, HID_, 512);
  transpose_to_bf16<<<dim3(512/32,  HID_/32), dim3(32,8), 0, stream>>>(Wv, wkvt + (size_t)512 * HID_, HID_, 512);
  transpose_to_bf16<<<dim3(HID_/32, HID_/32), dim3(32,8), 0, stream>>>(Wphi, wpt, HID_, HID_);
  transpose_to_bf16<<<dim3(HID_/32, HID_/32), dim3(32,8), 0, stream>>>(Wo, wot, HID_, HID_);
  // 3-4. Q projection + fused KV projection
  gemm_bt<<<dim3(HID_/128, M/128), 256, 0, stream>>>(hsb, wqt, qlin, (int)M, HID_, HID_);
  gemm_bt<<<dim3(1024/128, M/128), 256, 0, stream>>>(hsb, wkvt, kvlin, (int)M, 1024, HID_);
  // 5-6. RoPE + kappa (+ layout to [B,H,S,D])
  rope_kappa_q<<<(int)(M * NH_ * 32 / 256), 256, 0, stream>>>(qlin, qk);
  rope_kappa_k<<<(int)(M * NKV_ * 32 / 256), 256, 0, stream>>>(kvlin, kk);
  // 7. global query (split-S + atomics)
  hipMemsetAsync(qg, 0, 64 * 64 * 4, stream);
  qg_mean<<<dim3(B_ * NH_, S_ / 256), 256, 0, stream>>>(qk, qg);
  // 8. logits + softmax * S
  logits_kernel<<<dim3(B_ * NH_, S_ / 256), 256, 0, stream>>>(kk, qg, alph);
  softmax_kernel<<<B_ * NH_, 256, 0, stream>>>(alph, alph);
  // 9. outer_sum (GQA-grouped, atomic-free partials into dead qlin region) + reduce
  outer_sum_kernel<<<dim3(B_ * NKV_, NCH_), 256, 0, stream>>>(kk, kvlin, alph, part);
  osum_reduce<<<256, 256, 0, stream>>>(part, osum);
  // 10. Xphi projection (reuses qlin region — partials dead after reduce)
  gemm_bt<<<dim3(HID_/128, M/128), 256, 0, stream>>>(hsb, wpt, qlin, (int)M, HID_, HID_);
  // 11. ctx = Xphi * (Qk @ osum)  -> bf16 (reuses kvlin region)
  ctx_kernel<<<dim3(B_ * NH_, S_ / 64), 256, 0, stream>>>(qk, osum, qlin, ctx);
  // 12. out = ctx @ Wo
  gemm_bt<<<dim3(HID_/128, M/128), 256, 0, stream>>>(ctx, wot, out, (int)M, HID_, HID_);
}